// Round 5
// baseline (447.366 us; speedup 1.0000x reference)
//
#include <hip/hip_runtime.h>
#include <math.h>

// ---------------------------------------------------------------------------
// EquivariantMPBlock, round 10.
//   Combined phase1: scatter (XCD-sharded) || node_feat in ONE kernel,
//     role = blockIdx&8 so any resident window is half/half (r6 lesson) and
//     shard = blockIdx&7 still matches round-robin XCD placement. Both roles
//     barrier-free. Saves min(scatter, feat) of serial time + a launch gap.
//   agg: startup latency chain cut - slots pre-zeroed (memset) so the slot
//     row loads unconditionally IN PARALLEL with cnt; cu padded with u=0 to
//     a multiple of 8 -> edge loop is pure 4-deep-gather pipeline, divergent
//     tail loop deleted (pad contributions are exactly 0 -> bit-identical).
//     __launch_bounds__(256,8) pins 8 waves/SIMD.
// ---------------------------------------------------------------------------

static constexpr float INV_SQRT_MUL = 0.17677669529663687f;   // 1/sqrt(32)
static constexpr float C_DOT = 0.10206207261596575f;          // 1/sqrt(96)
static constexpr float C_SCL = 0.07216878364870322f;          // 1/sqrt(192)
static constexpr float C_CRS = 0.05103103630798288f;          // 1/sqrt(384)
static constexpr float SQRT3 = 1.7320508075688772f;
static constexpr int MAXDEG = 48;
static constexpr int COMB_B = 2048;          // combined grid; half scatter, half feat
static constexpr int CNT_WORDS = 8 * 16384;  // sharded cnt layout

#define WS_ALIGN(x) (((x) + 255) & ~(size_t)255)
#define CIDX(r) ((((r) & 7) << 14) | ((r) >> 3))

__device__ __forceinline__ unsigned short f2bf(float v) {
    unsigned int b = __float_as_uint(v);
    b += 0x7FFFu + ((b >> 16) & 1u);   // RNE
    return (unsigned short)(b >> 16);
}
__device__ __forceinline__ float bf2f(unsigned short u) {
    return __uint_as_float(((unsigned int)u) << 16);
}

// --- fused agg weights + transposed node weights (1 block) -------------------
// Wall[0..3071]: fused. Wall[3072..5119]: WnsT (64x32). Wall[5120..6143]: WnvT.
__global__ __launch_bounds__(1024)
void fuse_w(const float* __restrict__ Wns, const float* __restrict__ Wnv,
            const float* __restrict__ Wtpd, const float* __restrict__ Wtps,
            const float* __restrict__ Wtpc, const float* __restrict__ Wms,
            const float* __restrict__ Wmv, float* __restrict__ Wall) {
    int t = threadIdx.x;
    int i = t >> 5, j = t & 31;
    float a = 0.f, b = 0.f, c = 0.f;
#pragma unroll
    for (int k = 0; k < 32; ++k) {
        a += Wtpd[i * 32 + k] * Wms[k * 32 + j];
        b += Wtps[i * 32 + k] * Wmv[k * 32 + j];
        c += Wtpc[i * 32 + k] * Wmv[k * 32 + j];
    }
    Wall[t]        = a * (C_DOT * INV_SQRT_MUL);
    Wall[1024 + t] = b * (C_SCL * INV_SQRT_MUL);
    Wall[2048 + t] = c * (C_CRS * INV_SQRT_MUL);
    int i2 = t >> 5, k2 = t & 31;
    Wall[3072 + t]        = Wns[k2 * 64 + i2];        // WnsT rows 0..31
    Wall[3072 + 1024 + t] = Wns[k2 * 64 + 32 + i2];   // WnsT rows 32..63
    Wall[5120 + t]        = Wnv[k2 * 32 + i2];        // WnvT
}

// --- combined: scatter role (bit3=0) || node_feat role (bit3=1) --------------
__global__ __launch_bounds__(256)
void phase1(const float* __restrict__ x, const float* __restrict__ WT,
            const int* __restrict__ eidx, ushort4* __restrict__ feat4,
            int* __restrict__ cnt, int* __restrict__ slots, int N, int E) {
    __shared__ float buf[4][64 * 36];     // feat staging (scatter blocks unused)
    int t = threadIdx.x;

    if ((blockIdx.x & 8) == 0) {
        // ---- XCD-sharded edge scatter --------------------------------------
        int shard = blockIdx.x & 7;                  // aligns with XCD id
        int sid = (int)(blockIdx.x >> 4);            // 0..127 within shard
        int tid = sid * 256 + t;
        const int SSTRIDE = (COMB_B / 16) * 256;     // 128 blocks/shard
        int Q = E >> 2;
        const int4* r4p = (const int4*)eidx;
        const int4* c4p = (const int4*)(eidx + E);
        for (int q = tid; q < Q; q += SSTRIDE) {
            int4 R = r4p[q];
            bool any = ((R.x & 7) == shard) | ((R.y & 7) == shard) |
                       ((R.z & 7) == shard) | ((R.w & 7) == shard);
            if (!any) continue;
            int4 C = c4p[q];
            int rr[4] = {R.x, R.y, R.z, R.w};
            int cc[4] = {C.x, C.y, C.z, C.w};
#pragma unroll
            for (int k = 0; k < 4; ++k) {
                if ((rr[k] & 7) == shard) {
                    int p = atomicAdd(&cnt[CIDX(rr[k])], 1);
                    if (p < MAXDEG) slots[(size_t)rr[k] * MAXDEG + p] = cc[k];
                }
            }
        }
        for (int e = (Q << 2) + tid; e < E; e += SSTRIDE) {   // tail
            int r = eidx[e];
            if ((r & 7) == shard) {
                int c = eidx[E + e];
                int p = atomicAdd(&cnt[CIDX(r)], 1);
                if (p < MAXDEG) slots[(size_t)r * MAXDEG + p] = c;
            }
        }
    } else {
        // ---- node features: wave-private 64-node tiles, no barriers --------
        int fid = (int)(((blockIdx.x >> 4) << 3) | (blockIdx.x & 7));  // 0..1023
        int wv = t >> 6, l = t & 63;
        float* bw = buf[wv];
        int nt = (N + 63) >> 6;
        int r0 = l >> 3, cw = (l & 7) << 2;
        const float* WnsT = WT;               // [64][32] (s rows then gate rows)
        const float* WnvT = WT + 2048;        // [32][32]

        for (int tile = fid * 4 + wv; tile < nt; tile += (COMB_B / 2) * 4) {
            int B = tile << 6;
            auto stage = [&](int w0) {
#pragma unroll
                for (int j = 0; j < 8; ++j) {
                    int row = j * 8 + r0;
                    int node = B + row;
                    float4 v = make_float4(0.f, 0.f, 0.f, 0.f);
                    if (node < N) v = *(const float4*)(x + (size_t)node * 128 + w0 + cw);
                    *(float4*)(bw + row * 36 + cw) = v;
                }
                __builtin_amdgcn_wave_barrier();
            };
            auto readrow = [&](float* dst) {      // own row -> 8x ds_read_b128
                const float4* rp = (const float4*)(bw + l * 36);
#pragma unroll
                for (int j = 0; j < 8; ++j) {
                    float4 q = rp[j];
                    dst[4*j] = q.x; dst[4*j+1] = q.y; dst[4*j+2] = q.z; dst[4*j+3] = q.w;
                }
                __builtin_amdgcn_wave_barrier();
            };

            // ---- s + gate ----
            float xs[32];
            stage(0); readrow(xs);
            unsigned int scp[16];
            float sig[32];
#pragma unroll 2
            for (int i = 0; i < 32; ++i) {
                float a = 0.f, g = 0.f;
#pragma unroll
                for (int k = 0; k < 32; ++k) {
                    a += xs[k] * WnsT[i * 32 + k];           // wave-uniform s_load
                    g += xs[k] * WnsT[(32 + i) * 32 + k];
                }
                a = fmaxf(a * INV_SQRT_MUL, 0.f);
                float s = 1.f / (1.f + __expf(-g * INV_SQRT_MUL));
                unsigned short s16 = f2bf(a);
                if ((i & 1) == 0) scp[i >> 1] = s16;
                else scp[i >> 1] |= ((unsigned int)s16) << 16;
                sig[i] = s * INV_SQRT_MUL;
            }
            // ---- v ----
            float xv[96];
            stage(32); readrow(xv);
            stage(64); readrow(xv + 32);
            stage(96); readrow(xv + 64);
            int node = B + l;
            bool liv = (node < N);
#pragma unroll 2
            for (int i = 0; i < 32; ++i) {
                float o0 = 0.f, o1 = 0.f, o2 = 0.f;
#pragma unroll
                for (int k = 0; k < 32; ++k) {
                    float w = WnvT[i * 32 + k];              // s_load
                    o0 += xv[3 * k + 0] * w;
                    o1 += xv[3 * k + 1] * w;
                    o2 += xv[3 * k + 2] * w;
                }
                float s = sig[i];
                unsigned int scw = scp[i >> 1];
                ushort4 pk;
                pk.x = (unsigned short)((i & 1) ? (scw >> 16) : (scw & 0xFFFFu));
                pk.y = f2bf(o0 * s); pk.z = f2bf(o1 * s); pk.w = f2bf(o2 * s);
                if (liv) feat4[(size_t)node * 32 + i] = pk;   // L2 assembles rows
            }
            __builtin_amdgcn_wave_barrier();   // protect bw before next tile
        }
    }
}

// --- agg: one wave per node, padded edge pipeline, parallel startup loads ----
__global__ __launch_bounds__(256, 8)
void agg(const float* __restrict__ x, const float* __restrict__ pos,
         const ushort4* __restrict__ feat4, const int* __restrict__ cnt,
         const int* __restrict__ slots, const float* __restrict__ Wall,
         const float* __restrict__ gamma, const float* __restrict__ beta,
         float* __restrict__ out, int N) {
    __shared__ float4 cu[4][MAXDEG];
    __shared__ float4 finA[4][32];
    __shared__ float4 finB[4][32];
    int t = threadIdx.x;
    int wv = t >> 6, lane = t & 63;
    int ch = lane & 31, slot = lane >> 5;
    int n = blockIdx.x * 4 + wv;
    bool live = (n < N);
    int nn = live ? n : 0;

    // independent startup loads, all in flight together (slots pre-zeroed)
    int deg = cnt[CIDX(nn)];
    int colr = (lane < MAXDEG) ? slots[(size_t)nn * MAXDEG + lane] : 0;
    float prx = pos[nn * 3 + 0], pry = pos[nn * 3 + 1], prz = pos[nn * 3 + 2];
    if (!live) deg = 0;
    int c = min(deg, MAXDEG);
    int cpad = (c + 7) & ~7;

    if (lane < c) {
        float rx = pos[colr * 3 + 0] - prx, ry = pos[colr * 3 + 1] - pry, rz = pos[colr * 3 + 2] - prz;
        float inv = rsqrtf(rx * rx + ry * ry + rz * rz + 1e-12f) * SQRT3;
        cu[wv][lane] = make_float4(ry * inv, rz * inv, rx * inv, __int_as_float(colr << 8));
    } else if (lane < MAXDEG) {
        cu[wv][lane] = make_float4(0.f, 0.f, 0.f, __int_as_float(0));   // pad: u=0
    }
    __builtin_amdgcn_wave_barrier();

    const char* featB = (const char*)feat4;
    unsigned int ch8 = (unsigned int)ch * 8u;
    const float4* cuw = cu[wv];
    float D = 0.f, S0 = 0.f, S1 = 0.f, S2 = 0.f, C0 = 0.f, C1 = 0.f, C2 = 0.f;

    for (int jb = 0; jb < cpad; jb += 8) {    // 4 edges per slot, no tail
        float4 q[4]; ushort4 f[4];
#pragma unroll
        for (int k = 0; k < 4; ++k) q[k] = cuw[jb + 2 * k + slot];
#pragma unroll
        for (int k = 0; k < 4; ++k)
            f[k] = *(const ushort4*)(featB + (__float_as_uint(q[k].w) + ch8));
#pragma unroll
        for (int k = 0; k < 4; ++k) {
            float u0 = q[k].x, u1 = q[k].y, u2 = q[k].z;
            float sj = bf2f(f[k].x);
            float h0 = bf2f(f[k].y), h1 = bf2f(f[k].z), h2 = bf2f(f[k].w);
            D  += h0 * u0 + h1 * u1 + h2 * u2;
            S0 += sj * u0; S1 += sj * u1; S2 += sj * u2;
            C0 += h1 * u2 - h2 * u1;
            C1 += h2 * u0 - h0 * u2;
            C2 += h0 * u1 - h1 * u0;
        }
    }

    // combine the two edge slots
    D  += __shfl_xor(D, 32);
    S0 += __shfl_xor(S0, 32); S1 += __shfl_xor(S1, 32); S2 += __shfl_xor(S2, 32);
    C0 += __shfl_xor(C0, 32); C1 += __shfl_xor(C1, 32); C2 += __shfl_xor(C2, 32);
    if (lane < 32) {
        finA[wv][ch] = make_float4(D, S0, S1, S2);
        finB[wv][ch] = make_float4(C0, C1, C2, 0.f);
    }
    __builtin_amdgcn_wave_barrier();

    // final 32x32 transform: slot s handles i = 16s..16s+15, then recombine
    float invdeg = 1.0f / (float)((deg > 0) ? deg : 1);
    float a0 = 0.f, aV0 = 0.f, aV1 = 0.f, aV2 = 0.f;
    int i0 = slot << 4;
#pragma unroll 8
    for (int ii = 0; ii < 16; ++ii) {
        int i = i0 + ii;
        float4 a = finA[wv][i];            // LDS broadcast within half-wave
        float4 b = finB[wv][i];
        float wd = Wall[i * 32 + ch];      // L1-resident
        float ws = Wall[1024 + i * 32 + ch];
        float wc = Wall[2048 + i * 32 + ch];
        a0  += a.x * wd;
        aV0 += a.y * ws + b.x * wc;
        aV1 += a.z * ws + b.y * wc;
        aV2 += a.w * ws + b.z * wc;
    }
    a0  += __shfl_xor(a0, 32);
    aV0 += __shfl_xor(aV0, 32); aV1 += __shfl_xor(aV1, 32); aV2 += __shfl_xor(aV2, 32);

    float vd = a0 * invdeg;
    float v0 = aV0 * invdeg, v1 = aV1 * invdeg, v2 = aV2 * invdeg;

    float s1 = vd + v0 + v1 + v2;
    float s2 = vd * vd + v0 * v0 + v1 * v1 + v2 * v2;
#pragma unroll
    for (int m = 16; m >= 1; m >>= 1) {    // within each 32-lane half
        s1 += __shfl_xor(s1, m);
        s2 += __shfl_xor(s2, m);
    }
    float mu = s1 * (1.f / 128.f);
    float var = s2 * (1.f / 128.f) - mu * mu;
    float rstd = rsqrtf(var + 1e-5f);

    if (live && lane < 32) {
        size_t base = (size_t)n * 128;
        int chv = 32 + ch * 3;
        float xv0 = __builtin_nontemporal_load(&x[base + ch]);
        float xa  = __builtin_nontemporal_load(&x[base + chv + 0]);
        float xb  = __builtin_nontemporal_load(&x[base + chv + 1]);
        float xc  = __builtin_nontemporal_load(&x[base + chv + 2]);
        __builtin_nontemporal_store(xv0 + (vd - mu) * rstd * gamma[ch] + beta[ch], &out[base + ch]);
        __builtin_nontemporal_store(xa + (v0 - mu) * rstd * gamma[chv + 0] + beta[chv + 0], &out[base + chv + 0]);
        __builtin_nontemporal_store(xb + (v1 - mu) * rstd * gamma[chv + 1] + beta[chv + 1], &out[base + chv + 1]);
        __builtin_nontemporal_store(xc + (v2 - mu) * rstd * gamma[chv + 2] + beta[chv + 2], &out[base + chv + 2]);
    }
}

// ---------------------------------------------------------------------------
extern "C" void kernel_launch(void* const* d_in, const int* in_sizes, int n_in,
                              void* d_out, int out_size, void* d_ws, size_t ws_size,
                              hipStream_t stream) {
    const float* x     = (const float*)d_in[0];
    const float* pos   = (const float*)d_in[1];
    const int*   eidx  = (const int*)d_in[2];
    const float* Wns   = (const float*)d_in[3];
    const float* Wnv   = (const float*)d_in[4];
    const float* Wtpd  = (const float*)d_in[5];
    const float* Wtps  = (const float*)d_in[6];
    const float* Wtpc  = (const float*)d_in[7];
    const float* Wms   = (const float*)d_in[8];
    const float* Wmv   = (const float*)d_in[9];
    const float* gamma = (const float*)d_in[10];
    const float* beta  = (const float*)d_in[11];
    float* out = (float*)d_out;

    int N = in_sizes[0] / 128;
    int E = in_sizes[2] / 2;

    char* ws = (char*)d_ws;
    size_t off = 0;
    unsigned short* feat = (unsigned short*)(ws + off); off += WS_ALIGN((size_t)N * 128 * 2);
    int*   cnt  = (int*)(ws + off);   off += WS_ALIGN((size_t)CNT_WORDS * 4);
    float* Wall = (float*)(ws + off); off += WS_ALIGN(6144 * 4);
    int*   slots = (int*)(ws + off);  // N*MAXDEG*4 + 256B pad (agg overreads 64 lanes)
    size_t slots_bytes = (size_t)N * MAXDEG * 4 + 256;

    hipMemsetAsync(cnt, 0, (size_t)CNT_WORDS * 4, stream);
    hipMemsetAsync(slots, 0, slots_bytes, stream);
    fuse_w<<<1, 1024, 0, stream>>>(Wns, Wnv, Wtpd, Wtps, Wtpc, Wms, Wmv, Wall);
    phase1<<<COMB_B, 256, 0, stream>>>(x, Wall + 3072, eidx, (ushort4*)feat, cnt, slots, N, E);
    agg<<<(N + 3) / 4, 256, 0, stream>>>(x, pos, (const ushort4*)feat, cnt, slots, Wall, gamma, beta, out, N);
}

// Round 6
// 369.755 us; speedup vs baseline: 1.2099x; 1.2099x over previous
//
#include <hip/hip_runtime.h>
#include <math.h>

// ---------------------------------------------------------------------------
// EquivariantMPBlock, round 11.
//   r10 lesson (counters): __launch_bounds__(256,8) capped VGPR at 32 ->
//   SCRATCH SPILLS in the edge pipeline (WRITE 50->225MB deterministic,
//   FETCH +108MB, no speedup). Fix: no min-waves bound, let compiler use ~60.
//   agg = r8 half-wave-per-node structure (beat r9 wave-per-node: 166 vs 171)
//     + r10's parallel startup (cnt || slot row || pos row in flight together)
//     + u=0 pad to multiple of 4 -> pure 4-deep gather pipeline, no tail.
//   slots memset DROPPED (pad cols never dereferenced - dead 19MB write).
//   phase1 combined scatter||feat kept (bounded <178us by r10 counters).
// ---------------------------------------------------------------------------

static constexpr float INV_SQRT_MUL = 0.17677669529663687f;   // 1/sqrt(32)
static constexpr float C_DOT = 0.10206207261596575f;          // 1/sqrt(96)
static constexpr float C_SCL = 0.07216878364870322f;          // 1/sqrt(192)
static constexpr float C_CRS = 0.05103103630798288f;          // 1/sqrt(384)
static constexpr float SQRT3 = 1.7320508075688772f;
static constexpr int MAXDEG = 48;
static constexpr int COMB_B = 2048;          // combined grid; half scatter, half feat
static constexpr int CNT_WORDS = 8 * 16384;  // sharded cnt layout

#define WS_ALIGN(x) (((x) + 255) & ~(size_t)255)
#define CIDX(r) ((((r) & 7) << 14) | ((r) >> 3))

__device__ __forceinline__ unsigned short f2bf(float v) {
    unsigned int b = __float_as_uint(v);
    b += 0x7FFFu + ((b >> 16) & 1u);   // RNE
    return (unsigned short)(b >> 16);
}
__device__ __forceinline__ float bf2f(unsigned short u) {
    return __uint_as_float(((unsigned int)u) << 16);
}

// --- fused agg weights + transposed node weights (1 block) -------------------
// Wall[0..3071]: fused. Wall[3072..5119]: WnsT (64x32). Wall[5120..6143]: WnvT.
__global__ __launch_bounds__(1024)
void fuse_w(const float* __restrict__ Wns, const float* __restrict__ Wnv,
            const float* __restrict__ Wtpd, const float* __restrict__ Wtps,
            const float* __restrict__ Wtpc, const float* __restrict__ Wms,
            const float* __restrict__ Wmv, float* __restrict__ Wall) {
    int t = threadIdx.x;
    int i = t >> 5, j = t & 31;
    float a = 0.f, b = 0.f, c = 0.f;
#pragma unroll
    for (int k = 0; k < 32; ++k) {
        a += Wtpd[i * 32 + k] * Wms[k * 32 + j];
        b += Wtps[i * 32 + k] * Wmv[k * 32 + j];
        c += Wtpc[i * 32 + k] * Wmv[k * 32 + j];
    }
    Wall[t]        = a * (C_DOT * INV_SQRT_MUL);
    Wall[1024 + t] = b * (C_SCL * INV_SQRT_MUL);
    Wall[2048 + t] = c * (C_CRS * INV_SQRT_MUL);
    int i2 = t >> 5, k2 = t & 31;
    Wall[3072 + t]        = Wns[k2 * 64 + i2];        // WnsT rows 0..31
    Wall[3072 + 1024 + t] = Wns[k2 * 64 + 32 + i2];   // WnsT rows 32..63
    Wall[5120 + t]        = Wnv[k2 * 32 + i2];        // WnvT
}

// --- combined: scatter role (bit3=0) || node_feat role (bit3=1) --------------
__global__ __launch_bounds__(256)
void phase1(const float* __restrict__ x, const float* __restrict__ WT,
            const int* __restrict__ eidx, ushort4* __restrict__ feat4,
            int* __restrict__ cnt, int* __restrict__ slots, int N, int E) {
    __shared__ float buf[4][64 * 36];     // feat staging (scatter blocks unused)
    int t = threadIdx.x;

    if ((blockIdx.x & 8) == 0) {
        // ---- XCD-sharded edge scatter --------------------------------------
        int shard = blockIdx.x & 7;                  // aligns with XCD id
        int sid = (int)(blockIdx.x >> 4);            // 0..127 within shard
        int tid = sid * 256 + t;
        const int SSTRIDE = (COMB_B / 16) * 256;     // 128 blocks/shard
        int Q = E >> 2;
        const int4* r4p = (const int4*)eidx;
        const int4* c4p = (const int4*)(eidx + E);
        for (int q = tid; q < Q; q += SSTRIDE) {
            int4 R = r4p[q];
            bool any = ((R.x & 7) == shard) | ((R.y & 7) == shard) |
                       ((R.z & 7) == shard) | ((R.w & 7) == shard);
            if (!any) continue;
            int4 C = c4p[q];
            int rr[4] = {R.x, R.y, R.z, R.w};
            int cc[4] = {C.x, C.y, C.z, C.w};
#pragma unroll
            for (int k = 0; k < 4; ++k) {
                if ((rr[k] & 7) == shard) {
                    int p = atomicAdd(&cnt[CIDX(rr[k])], 1);
                    if (p < MAXDEG) slots[(size_t)rr[k] * MAXDEG + p] = cc[k];
                }
            }
        }
        for (int e = (Q << 2) + tid; e < E; e += SSTRIDE) {   // tail
            int r = eidx[e];
            if ((r & 7) == shard) {
                int c = eidx[E + e];
                int p = atomicAdd(&cnt[CIDX(r)], 1);
                if (p < MAXDEG) slots[(size_t)r * MAXDEG + p] = c;
            }
        }
    } else {
        // ---- node features: wave-private 64-node tiles, no barriers --------
        int fid = (int)(((blockIdx.x >> 4) << 3) | (blockIdx.x & 7));  // 0..1023
        int wv = t >> 6, l = t & 63;
        float* bw = buf[wv];
        int nt = (N + 63) >> 6;
        int r0 = l >> 3, cw = (l & 7) << 2;
        const float* WnsT = WT;               // [64][32] (s rows then gate rows)
        const float* WnvT = WT + 2048;        // [32][32]

        for (int tile = fid * 4 + wv; tile < nt; tile += (COMB_B / 2) * 4) {
            int B = tile << 6;
            auto stage = [&](int w0) {
#pragma unroll
                for (int j = 0; j < 8; ++j) {
                    int row = j * 8 + r0;
                    int node = B + row;
                    float4 v = make_float4(0.f, 0.f, 0.f, 0.f);
                    if (node < N) v = *(const float4*)(x + (size_t)node * 128 + w0 + cw);
                    *(float4*)(bw + row * 36 + cw) = v;
                }
                __builtin_amdgcn_wave_barrier();
            };
            auto readrow = [&](float* dst) {      // own row -> 8x ds_read_b128
                const float4* rp = (const float4*)(bw + l * 36);
#pragma unroll
                for (int j = 0; j < 8; ++j) {
                    float4 q = rp[j];
                    dst[4*j] = q.x; dst[4*j+1] = q.y; dst[4*j+2] = q.z; dst[4*j+3] = q.w;
                }
                __builtin_amdgcn_wave_barrier();
            };

            // ---- s + gate ----
            float xs[32];
            stage(0); readrow(xs);
            unsigned int scp[16];
            float sig[32];
#pragma unroll 2
            for (int i = 0; i < 32; ++i) {
                float a = 0.f, g = 0.f;
#pragma unroll
                for (int k = 0; k < 32; ++k) {
                    a += xs[k] * WnsT[i * 32 + k];           // wave-uniform s_load
                    g += xs[k] * WnsT[(32 + i) * 32 + k];
                }
                a = fmaxf(a * INV_SQRT_MUL, 0.f);
                float s = 1.f / (1.f + __expf(-g * INV_SQRT_MUL));
                unsigned short s16 = f2bf(a);
                if ((i & 1) == 0) scp[i >> 1] = s16;
                else scp[i >> 1] |= ((unsigned int)s16) << 16;
                sig[i] = s * INV_SQRT_MUL;
            }
            // ---- v ----
            float xv[96];
            stage(32); readrow(xv);
            stage(64); readrow(xv + 32);
            stage(96); readrow(xv + 64);
            int node = B + l;
            bool liv = (node < N);
#pragma unroll 2
            for (int i = 0; i < 32; ++i) {
                float o0 = 0.f, o1 = 0.f, o2 = 0.f;
#pragma unroll
                for (int k = 0; k < 32; ++k) {
                    float w = WnvT[i * 32 + k];              // s_load
                    o0 += xv[3 * k + 0] * w;
                    o1 += xv[3 * k + 1] * w;
                    o2 += xv[3 * k + 2] * w;
                }
                float s = sig[i];
                unsigned int scw = scp[i >> 1];
                ushort4 pk;
                pk.x = (unsigned short)((i & 1) ? (scw >> 16) : (scw & 0xFFFFu));
                pk.y = f2bf(o0 * s); pk.z = f2bf(o1 * s); pk.w = f2bf(o2 * s);
                if (liv) feat4[(size_t)node * 32 + i] = pk;   // L2 assembles rows
            }
            __builtin_amdgcn_wave_barrier();   // protect bw before next tile
        }
    }
}

// --- agg: half-wave per node (r8 structure), parallel startup, padded loop ---
__global__ __launch_bounds__(256)
void agg(const float* __restrict__ x, const float* __restrict__ pos,
         const ushort4* __restrict__ feat4, const int* __restrict__ cnt,
         const int* __restrict__ slots, const float* __restrict__ Wall,
         const float* __restrict__ gamma, const float* __restrict__ beta,
         float* __restrict__ out, int N) {
    __shared__ float4 cu[8][MAXDEG];
    __shared__ float4 finA[8][32];
    __shared__ float4 finB[8][32];
    int t = threadIdx.x;
    int hw = t >> 5, lane = t & 31;
    int n = blockIdx.x * 8 + hw;
    bool live = (n < N);
    int nn = live ? n : 0;

    // independent startup loads, all in flight together
    int deg = cnt[CIDX(nn)];
    size_t srow = (size_t)nn * MAXDEG;
    int col0 = slots[srow + lane];                  // unconditional; used iff < c
    int col1 = slots[srow + 32 + (lane & 15)];      // lanes 0..15 meaningful
    float prx = pos[nn * 3 + 0], pry = pos[nn * 3 + 1], prz = pos[nn * 3 + 2];
    if (!live) deg = 0;
    int c = min(deg, MAXDEG);
    int cpad = (c + 3) & ~3;

    if (lane < c) {
        float rx = pos[col0 * 3 + 0] - prx, ry = pos[col0 * 3 + 1] - pry, rz = pos[col0 * 3 + 2] - prz;
        float inv = rsqrtf(rx * rx + ry * ry + rz * rz + 1e-12f) * SQRT3;
        cu[hw][lane] = make_float4(ry * inv, rz * inv, rx * inv, __int_as_float(col0 << 8));
    } else {
        cu[hw][lane] = make_float4(0.f, 0.f, 0.f, __int_as_float(0));   // pad u=0
    }
    if (lane < 16) {
        int idx = 32 + lane;
        if (idx < c) {
            float rx = pos[col1 * 3 + 0] - prx, ry = pos[col1 * 3 + 1] - pry, rz = pos[col1 * 3 + 2] - prz;
            float inv = rsqrtf(rx * rx + ry * ry + rz * rz + 1e-12f) * SQRT3;
            cu[hw][idx] = make_float4(ry * inv, rz * inv, rx * inv, __int_as_float(col1 << 8));
        } else {
            cu[hw][idx] = make_float4(0.f, 0.f, 0.f, __int_as_float(0));
        }
    }
    __builtin_amdgcn_wave_barrier();

    const char* featB = (const char*)feat4;
    unsigned int ch8 = (unsigned int)lane * 8u;
    const float4* cuw = cu[hw];
    float D = 0.f, S0 = 0.f, S1 = 0.f, S2 = 0.f, C0 = 0.f, C1 = 0.f, C2 = 0.f;

    for (int jb = 0; jb < cpad; jb += 4) {    // pure 4-deep gather pipeline
        float4 q[4]; ushort4 f[4];
#pragma unroll
        for (int k = 0; k < 4; ++k) q[k] = cuw[jb + k];          // LDS broadcast
#pragma unroll
        for (int k = 0; k < 4; ++k)
            f[k] = *(const ushort4*)(featB + (__float_as_uint(q[k].w) + ch8));
#pragma unroll
        for (int k = 0; k < 4; ++k) {
            float u0 = q[k].x, u1 = q[k].y, u2 = q[k].z;
            float sj = bf2f(f[k].x);
            float h0 = bf2f(f[k].y), h1 = bf2f(f[k].z), h2 = bf2f(f[k].w);
            D  += h0 * u0 + h1 * u1 + h2 * u2;
            S0 += sj * u0; S1 += sj * u1; S2 += sj * u2;
            C0 += h1 * u2 - h2 * u1;
            C1 += h2 * u0 - h0 * u2;
            C2 += h0 * u1 - h1 * u0;
        }
    }

    finA[hw][lane] = make_float4(D, S0, S1, S2);
    finB[hw][lane] = make_float4(C0, C1, C2, 0.f);
    __builtin_amdgcn_wave_barrier();

    float invdeg = 1.0f / (float)((deg > 0) ? deg : 1);
    float a0 = 0.f, aV0 = 0.f, aV1 = 0.f, aV2 = 0.f;
#pragma unroll 8
    for (int i = 0; i < 32; ++i) {
        float4 a = finA[hw][i];            // broadcast within half-wave
        float4 b = finB[hw][i];
        float wd = Wall[i * 32 + lane];    // L1-resident
        float ws = Wall[1024 + i * 32 + lane];
        float wc = Wall[2048 + i * 32 + lane];
        a0  += a.x * wd;
        aV0 += a.y * ws + b.x * wc;
        aV1 += a.z * ws + b.y * wc;
        aV2 += a.w * ws + b.z * wc;
    }
    float vd = a0 * invdeg;
    float v0 = aV0 * invdeg, v1 = aV1 * invdeg, v2 = aV2 * invdeg;

    float s1 = vd + v0 + v1 + v2;
    float s2 = vd * vd + v0 * v0 + v1 * v1 + v2 * v2;
#pragma unroll
    for (int m = 16; m >= 1; m >>= 1) {
        s1 += __shfl_xor(s1, m);
        s2 += __shfl_xor(s2, m);
    }
    float mu = s1 * (1.f / 128.f);
    float var = s2 * (1.f / 128.f) - mu * mu;
    float rstd = rsqrtf(var + 1e-5f);

    if (live) {
        size_t base = (size_t)n * 128;
        int chv = 32 + lane * 3;
        float xv0 = __builtin_nontemporal_load(&x[base + lane]);
        float xa  = __builtin_nontemporal_load(&x[base + chv + 0]);
        float xb  = __builtin_nontemporal_load(&x[base + chv + 1]);
        float xc  = __builtin_nontemporal_load(&x[base + chv + 2]);
        __builtin_nontemporal_store(xv0 + (vd - mu) * rstd * gamma[lane] + beta[lane], &out[base + lane]);
        __builtin_nontemporal_store(xa + (v0 - mu) * rstd * gamma[chv + 0] + beta[chv + 0], &out[base + chv + 0]);
        __builtin_nontemporal_store(xb + (v1 - mu) * rstd * gamma[chv + 1] + beta[chv + 1], &out[base + chv + 1]);
        __builtin_nontemporal_store(xc + (v2 - mu) * rstd * gamma[chv + 2] + beta[chv + 2], &out[base + chv + 2]);
    }
}

// ---------------------------------------------------------------------------
extern "C" void kernel_launch(void* const* d_in, const int* in_sizes, int n_in,
                              void* d_out, int out_size, void* d_ws, size_t ws_size,
                              hipStream_t stream) {
    const float* x     = (const float*)d_in[0];
    const float* pos   = (const float*)d_in[1];
    const int*   eidx  = (const int*)d_in[2];
    const float* Wns   = (const float*)d_in[3];
    const float* Wnv   = (const float*)d_in[4];
    const float* Wtpd  = (const float*)d_in[5];
    const float* Wtps  = (const float*)d_in[6];
    const float* Wtpc  = (const float*)d_in[7];
    const float* Wms   = (const float*)d_in[8];
    const float* Wmv   = (const float*)d_in[9];
    const float* gamma = (const float*)d_in[10];
    const float* beta  = (const float*)d_in[11];
    float* out = (float*)d_out;

    int N = in_sizes[0] / 128;
    int E = in_sizes[2] / 2;

    char* ws = (char*)d_ws;
    size_t off = 0;
    unsigned short* feat = (unsigned short*)(ws + off); off += WS_ALIGN((size_t)N * 128 * 2);
    int*   cnt  = (int*)(ws + off);   off += WS_ALIGN((size_t)CNT_WORDS * 4);
    float* Wall = (float*)(ws + off); off += WS_ALIGN(6144 * 4);
    int*   slots = (int*)(ws + off);  // N * MAXDEG * 4B

    hipMemsetAsync(cnt, 0, (size_t)CNT_WORDS * 4, stream);
    fuse_w<<<1, 1024, 0, stream>>>(Wns, Wnv, Wtpd, Wtps, Wtpc, Wms, Wmv, Wall);
    phase1<<<COMB_B, 256, 0, stream>>>(x, Wall + 3072, eidx, (ushort4*)feat, cnt, slots, N, E);
    agg<<<(N + 7) / 8, 256, 0, stream>>>(x, pos, (const ushort4*)feat, cnt, slots, Wall, gamma, beta, out, N);
}

// Round 7
// 352.254 us; speedup vs baseline: 1.2700x; 1.0497x over previous
//
#include <hip/hip_runtime.h>
#include <math.h>

// ---------------------------------------------------------------------------
// EquivariantMPBlock, round 12.
//   r11 counters: combined phase1 broke BOTH scatter enablers -
//     (a) feat's 77MB stream evicted the sharded slot lines from L2
//         (WRITE 150-166MB vs ~50 expected), and
//     (b) the kernel-wide 36.9KB static LDS was charged to scatter blocks
//         too -> 4 blocks/CU -> occupancy 15%, VALUBusy 11%.
//   Fix: SEPARATE kernels, each in its best config:
//     scatter: zero LDS, ~32 VGPR, full occupancy, XCD-sharded slots+cnt
//       L2-resident (r8-proven: WRITE collapses to slot payload).
//     feat: r11 wave-private-tile body in 128-thr/2-wave blocks (18.4KB LDS,
//       ~3 blocks/CU), run right before agg so feat4 is L2/L3-warm.
//     cnt-zero folded into fuse_zero (one less dispatch).
//   agg: r11 half-wave-per-node (dropped below top-5 visibility; untouched).
// ---------------------------------------------------------------------------

static constexpr float INV_SQRT_MUL = 0.17677669529663687f;   // 1/sqrt(32)
static constexpr float C_DOT = 0.10206207261596575f;          // 1/sqrt(96)
static constexpr float C_SCL = 0.07216878364870322f;          // 1/sqrt(192)
static constexpr float C_CRS = 0.05103103630798288f;          // 1/sqrt(384)
static constexpr float SQRT3 = 1.7320508075688772f;
static constexpr int MAXDEG = 48;
static constexpr int SCAT_B = 2048;          // 256 blocks per shard
static constexpr int CNT_WORDS = 8 * 16384;  // sharded cnt layout

#define WS_ALIGN(x) (((x) + 255) & ~(size_t)255)
#define CIDX(r) ((((r) & 7) << 14) | ((r) >> 3))

__device__ __forceinline__ unsigned short f2bf(float v) {
    unsigned int b = __float_as_uint(v);
    b += 0x7FFFu + ((b >> 16) & 1u);   // RNE
    return (unsigned short)(b >> 16);
}
__device__ __forceinline__ float bf2f(unsigned short u) {
    return __uint_as_float(((unsigned int)u) << 16);
}

// --- fused agg weights + transposed node weights + zero cnt ------------------
// Wall[0..3071]: fused. Wall[3072..5119]: WnsT (64x32). Wall[5120..6143]: WnvT.
__global__ __launch_bounds__(1024)
void fuse_zero(const float* __restrict__ Wns, const float* __restrict__ Wnv,
               const float* __restrict__ Wtpd, const float* __restrict__ Wtps,
               const float* __restrict__ Wtpc, const float* __restrict__ Wms,
               const float* __restrict__ Wmv, float* __restrict__ Wall,
               int* __restrict__ cnt) {
    int t = threadIdx.x;
    if (blockIdx.x == 0) {
        int i = t >> 5, j = t & 31;
        float a = 0.f, b = 0.f, c = 0.f;
#pragma unroll
        for (int k = 0; k < 32; ++k) {
            a += Wtpd[i * 32 + k] * Wms[k * 32 + j];
            b += Wtps[i * 32 + k] * Wmv[k * 32 + j];
            c += Wtpc[i * 32 + k] * Wmv[k * 32 + j];
        }
        Wall[t]        = a * (C_DOT * INV_SQRT_MUL);
        Wall[1024 + t] = b * (C_SCL * INV_SQRT_MUL);
        Wall[2048 + t] = c * (C_CRS * INV_SQRT_MUL);
        int i2 = t >> 5, k2 = t & 31;
        Wall[3072 + t]        = Wns[k2 * 64 + i2];        // WnsT rows 0..31
        Wall[3072 + 1024 + t] = Wns[k2 * 64 + 32 + i2];   // WnsT rows 32..63
        Wall[5120 + t]        = Wnv[k2 * 32 + i2];        // WnvT
    } else {
        int i = (blockIdx.x - 1) * 1024 + t;
        if (i < CNT_WORDS) cnt[i] = 0;
    }
}

// --- XCD-sharded edge scatter: zero LDS, full occupancy ----------------------
__global__ __launch_bounds__(256)
void scatter(const int* __restrict__ eidx, int* __restrict__ cnt,
             int* __restrict__ slots, int E) {
    int shard = blockIdx.x & 7;                    // aligns with round-robin XCD
    int tid = (blockIdx.x >> 3) * 256 + threadIdx.x;
    const int SSTRIDE = (SCAT_B / 8) * 256;
    int Q = E >> 2;
    const int4* r4p = (const int4*)eidx;
    const int4* c4p = (const int4*)(eidx + E);
    for (int q = tid; q < Q; q += SSTRIDE) {
        int4 R = r4p[q];
        bool any = ((R.x & 7) == shard) | ((R.y & 7) == shard) |
                   ((R.z & 7) == shard) | ((R.w & 7) == shard);
        if (!any) continue;
        int4 C = c4p[q];
        int rr[4] = {R.x, R.y, R.z, R.w};
        int cc[4] = {C.x, C.y, C.z, C.w};
#pragma unroll
        for (int k = 0; k < 4; ++k) {
            if ((rr[k] & 7) == shard) {
                int p = atomicAdd(&cnt[CIDX(rr[k])], 1);
                if (p < MAXDEG) slots[(size_t)rr[k] * MAXDEG + p] = cc[k];
            }
        }
    }
    for (int e = (Q << 2) + tid; e < E; e += SSTRIDE) {   // tail
        int r = eidx[e];
        if ((r & 7) == shard) {
            int c = eidx[E + e];
            int p = atomicAdd(&cnt[CIDX(r)], 1);
            if (p < MAXDEG) slots[(size_t)r * MAXDEG + p] = c;
        }
    }
}

// --- node features: 2 wave-private 64-node tiles per 128-thr block -----------
__global__ __launch_bounds__(128)
void node_feat(const float* __restrict__ x, const float* __restrict__ WT,
               ushort4* __restrict__ feat4, int N) {
    __shared__ float buf[2][64 * 36];     // 9.2KB per wave
    int t = threadIdx.x;
    int wv = t >> 6, l = t & 63;
    float* bw = buf[wv];
    int nt = (N + 63) >> 6;
    int tile = blockIdx.x * 2 + wv;
    if (tile >= nt) return;
    int B = tile << 6;
    int r0 = l >> 3, cw = (l & 7) << 2;
    const float* WnsT = WT;               // [64][32] (s rows then gate rows)
    const float* WnvT = WT + 2048;        // [32][32]

    auto stage = [&](int w0) {
#pragma unroll
        for (int j = 0; j < 8; ++j) {
            int row = j * 8 + r0;
            int node = B + row;
            float4 v = make_float4(0.f, 0.f, 0.f, 0.f);
            if (node < N) v = *(const float4*)(x + (size_t)node * 128 + w0 + cw);
            *(float4*)(bw + row * 36 + cw) = v;
        }
        __builtin_amdgcn_wave_barrier();
    };
    auto readrow = [&](float* dst) {      // own row -> 8x ds_read_b128
        const float4* rp = (const float4*)(bw + l * 36);
#pragma unroll
        for (int j = 0; j < 8; ++j) {
            float4 q = rp[j];
            dst[4*j] = q.x; dst[4*j+1] = q.y; dst[4*j+2] = q.z; dst[4*j+3] = q.w;
        }
        __builtin_amdgcn_wave_barrier();
    };

    // ---- s + gate ----
    float xs[32];
    stage(0); readrow(xs);
    unsigned int scp[16];
    float sig[32];
#pragma unroll 2
    for (int i = 0; i < 32; ++i) {
        float a = 0.f, g = 0.f;
#pragma unroll
        for (int k = 0; k < 32; ++k) {
            a += xs[k] * WnsT[i * 32 + k];           // wave-uniform -> s_load
            g += xs[k] * WnsT[(32 + i) * 32 + k];
        }
        a = fmaxf(a * INV_SQRT_MUL, 0.f);
        float s = 1.f / (1.f + __expf(-g * INV_SQRT_MUL));
        unsigned short s16 = f2bf(a);
        if ((i & 1) == 0) scp[i >> 1] = s16;
        else scp[i >> 1] |= ((unsigned int)s16) << 16;
        sig[i] = s * INV_SQRT_MUL;
    }
    // ---- v ----
    float xv[96];
    stage(32); readrow(xv);
    stage(64); readrow(xv + 32);
    stage(96); readrow(xv + 64);
    int node = B + l;
    bool liv = (node < N);
#pragma unroll 2
    for (int i = 0; i < 32; ++i) {
        float o0 = 0.f, o1 = 0.f, o2 = 0.f;
#pragma unroll
        for (int k = 0; k < 32; ++k) {
            float w = WnvT[i * 32 + k];              // s_load
            o0 += xv[3 * k + 0] * w;
            o1 += xv[3 * k + 1] * w;
            o2 += xv[3 * k + 2] * w;
        }
        float s = sig[i];
        unsigned int scw = scp[i >> 1];
        ushort4 pk;
        pk.x = (unsigned short)((i & 1) ? (scw >> 16) : (scw & 0xFFFFu));
        pk.y = f2bf(o0 * s); pk.z = f2bf(o1 * s); pk.w = f2bf(o2 * s);
        if (liv) feat4[(size_t)node * 32 + i] = pk;   // L2 assembles rows
    }
}

// --- agg: half-wave per node, parallel startup, padded gather pipeline -------
__global__ __launch_bounds__(256)
void agg(const float* __restrict__ x, const float* __restrict__ pos,
         const ushort4* __restrict__ feat4, const int* __restrict__ cnt,
         const int* __restrict__ slots, const float* __restrict__ Wall,
         const float* __restrict__ gamma, const float* __restrict__ beta,
         float* __restrict__ out, int N) {
    __shared__ float4 cu[8][MAXDEG];
    __shared__ float4 finA[8][32];
    __shared__ float4 finB[8][32];
    int t = threadIdx.x;
    int hw = t >> 5, lane = t & 31;
    int n = blockIdx.x * 8 + hw;
    bool live = (n < N);
    int nn = live ? n : 0;

    // independent startup loads, all in flight together
    int deg = cnt[CIDX(nn)];
    size_t srow = (size_t)nn * MAXDEG;
    int col0 = slots[srow + lane];                  // unconditional; used iff < c
    int col1 = slots[srow + 32 + (lane & 15)];      // lanes 0..15 meaningful
    float prx = pos[nn * 3 + 0], pry = pos[nn * 3 + 1], prz = pos[nn * 3 + 2];
    if (!live) deg = 0;
    int c = min(deg, MAXDEG);
    int cpad = (c + 3) & ~3;

    if (lane < c) {
        float rx = pos[col0 * 3 + 0] - prx, ry = pos[col0 * 3 + 1] - pry, rz = pos[col0 * 3 + 2] - prz;
        float inv = rsqrtf(rx * rx + ry * ry + rz * rz + 1e-12f) * SQRT3;
        cu[hw][lane] = make_float4(ry * inv, rz * inv, rx * inv, __int_as_float(col0 << 8));
    } else {
        cu[hw][lane] = make_float4(0.f, 0.f, 0.f, __int_as_float(0));   // pad u=0
    }
    if (lane < 16) {
        int idx = 32 + lane;
        if (idx < c) {
            float rx = pos[col1 * 3 + 0] - prx, ry = pos[col1 * 3 + 1] - pry, rz = pos[col1 * 3 + 2] - prz;
            float inv = rsqrtf(rx * rx + ry * ry + rz * rz + 1e-12f) * SQRT3;
            cu[hw][idx] = make_float4(ry * inv, rz * inv, rx * inv, __int_as_float(col1 << 8));
        } else {
            cu[hw][idx] = make_float4(0.f, 0.f, 0.f, __int_as_float(0));
        }
    }
    __builtin_amdgcn_wave_barrier();

    const char* featB = (const char*)feat4;
    unsigned int ch8 = (unsigned int)lane * 8u;
    const float4* cuw = cu[hw];
    float D = 0.f, S0 = 0.f, S1 = 0.f, S2 = 0.f, C0 = 0.f, C1 = 0.f, C2 = 0.f;

    for (int jb = 0; jb < cpad; jb += 4) {    // pure 4-deep gather pipeline
        float4 q[4]; ushort4 f[4];
#pragma unroll
        for (int k = 0; k < 4; ++k) q[k] = cuw[jb + k];          // LDS broadcast
#pragma unroll
        for (int k = 0; k < 4; ++k)
            f[k] = *(const ushort4*)(featB + (__float_as_uint(q[k].w) + ch8));
#pragma unroll
        for (int k = 0; k < 4; ++k) {
            float u0 = q[k].x, u1 = q[k].y, u2 = q[k].z;
            float sj = bf2f(f[k].x);
            float h0 = bf2f(f[k].y), h1 = bf2f(f[k].z), h2 = bf2f(f[k].w);
            D  += h0 * u0 + h1 * u1 + h2 * u2;
            S0 += sj * u0; S1 += sj * u1; S2 += sj * u2;
            C0 += h1 * u2 - h2 * u1;
            C1 += h2 * u0 - h0 * u2;
            C2 += h0 * u1 - h1 * u0;
        }
    }

    finA[hw][lane] = make_float4(D, S0, S1, S2);
    finB[hw][lane] = make_float4(C0, C1, C2, 0.f);
    __builtin_amdgcn_wave_barrier();

    float invdeg = 1.0f / (float)((deg > 0) ? deg : 1);
    float a0 = 0.f, aV0 = 0.f, aV1 = 0.f, aV2 = 0.f;
#pragma unroll 8
    for (int i = 0; i < 32; ++i) {
        float4 a = finA[hw][i];            // broadcast within half-wave
        float4 b = finB[hw][i];
        float wd = Wall[i * 32 + lane];    // L1-resident
        float ws = Wall[1024 + i * 32 + lane];
        float wc = Wall[2048 + i * 32 + lane];
        a0  += a.x * wd;
        aV0 += a.y * ws + b.x * wc;
        aV1 += a.z * ws + b.y * wc;
        aV2 += a.w * ws + b.z * wc;
    }
    float vd = a0 * invdeg;
    float v0 = aV0 * invdeg, v1 = aV1 * invdeg, v2 = aV2 * invdeg;

    float s1 = vd + v0 + v1 + v2;
    float s2 = vd * vd + v0 * v0 + v1 * v1 + v2 * v2;
#pragma unroll
    for (int m = 16; m >= 1; m >>= 1) {
        s1 += __shfl_xor(s1, m);
        s2 += __shfl_xor(s2, m);
    }
    float mu = s1 * (1.f / 128.f);
    float var = s2 * (1.f / 128.f) - mu * mu;
    float rstd = rsqrtf(var + 1e-5f);

    if (live) {
        size_t base = (size_t)n * 128;
        int chv = 32 + lane * 3;
        float xv0 = __builtin_nontemporal_load(&x[base + lane]);
        float xa  = __builtin_nontemporal_load(&x[base + chv + 0]);
        float xb  = __builtin_nontemporal_load(&x[base + chv + 1]);
        float xc  = __builtin_nontemporal_load(&x[base + chv + 2]);
        __builtin_nontemporal_store(xv0 + (vd - mu) * rstd * gamma[lane] + beta[lane], &out[base + lane]);
        __builtin_nontemporal_store(xa + (v0 - mu) * rstd * gamma[chv + 0] + beta[chv + 0], &out[base + chv + 0]);
        __builtin_nontemporal_store(xb + (v1 - mu) * rstd * gamma[chv + 1] + beta[chv + 1], &out[base + chv + 1]);
        __builtin_nontemporal_store(xc + (v2 - mu) * rstd * gamma[chv + 2] + beta[chv + 2], &out[base + chv + 2]);
    }
}

// ---------------------------------------------------------------------------
extern "C" void kernel_launch(void* const* d_in, const int* in_sizes, int n_in,
                              void* d_out, int out_size, void* d_ws, size_t ws_size,
                              hipStream_t stream) {
    const float* x     = (const float*)d_in[0];
    const float* pos   = (const float*)d_in[1];
    const int*   eidx  = (const int*)d_in[2];
    const float* Wns   = (const float*)d_in[3];
    const float* Wnv   = (const float*)d_in[4];
    const float* Wtpd  = (const float*)d_in[5];
    const float* Wtps  = (const float*)d_in[6];
    const float* Wtpc  = (const float*)d_in[7];
    const float* Wms   = (const float*)d_in[8];
    const float* Wmv   = (const float*)d_in[9];
    const float* gamma = (const float*)d_in[10];
    const float* beta  = (const float*)d_in[11];
    float* out = (float*)d_out;

    int N = in_sizes[0] / 128;
    int E = in_sizes[2] / 2;

    char* ws = (char*)d_ws;
    size_t off = 0;
    unsigned short* feat = (unsigned short*)(ws + off); off += WS_ALIGN((size_t)N * 128 * 2);
    int*   cnt  = (int*)(ws + off);   off += WS_ALIGN((size_t)CNT_WORDS * 4);
    float* Wall = (float*)(ws + off); off += WS_ALIGN(6144 * 4);
    int*   slots = (int*)(ws + off);  // N * MAXDEG * 4B

    int zb = 1 + (CNT_WORDS + 1023) / 1024;
    fuse_zero<<<zb, 1024, 0, stream>>>(Wns, Wnv, Wtpd, Wtps, Wtpc, Wms, Wmv, Wall, cnt);
    scatter<<<SCAT_B, 256, 0, stream>>>(eidx, cnt, slots, E);
    int nt = (N + 63) >> 6;
    node_feat<<<(nt + 1) / 2, 128, 0, stream>>>(x, Wall + 3072, (ushort4*)feat, N);
    agg<<<(N + 7) / 8, 256, 0, stream>>>(x, pos, (const ushort4*)feat, cnt, slots, Wall, gamma, beta, out, N);
}